// Round 11
// baseline (217.651 us; speedup 1.0000x reference)
//
#include <hip/hip_runtime.h>
#include <hip/hip_bf16.h>
#include <stdint.h>

#define NQ 32
#define NCLS 5
#define SHOT 5
#define NIMG 57          // 32 query + 25 support
#define P1 7056          // 84*84
#define P2 1764          // 42*42
#define P3 441           // 21*21
#define MM (SHOT*P3)     // 2205
#define EPSB 1e-5f
#define SLOPE 0.2f
#define NEGINF -3.4e38f
#define NREP 32          // stats atomic replication factor
#define MSPAN 1152       // sim m-range rows per block (mr=0: 18 full; mr=1: 16 full + 29)
#define MRNG 2           // m-ranges (2*1152 >= 2205) -> 1280 blocks
#define QBLK 128         // sim q rows per block (2 groups of 16 per wave)
#define NQB 4            // ceil(441/128)
#define QG 2             // q-groups per wave
#define SLS 72           // sim LDS row stride in ushorts
#define BNPIX 32         // bnnorm pixels per block

typedef __attribute__((ext_vector_type(8))) short short8;
typedef __attribute__((ext_vector_type(4))) float f32x4;

__device__ __forceinline__ unsigned short bf16bits(float v)
{
    __hip_bfloat16 h = __float2bfloat16(v);
    return *reinterpret_cast<unsigned short*>(&h);
}
__device__ __forceinline__ float bits2f(unsigned short u)
{
    unsigned int x = ((unsigned int)u) << 16;
    return *reinterpret_cast<float*>(&x);
}

// ---------------- all weight packs + zero stats sums, one launch ----------------
__global__ void pack_all_k(const float* __restrict__ w1, const float* __restrict__ w2,
                           const float* __restrict__ w3, const float* __restrict__ w4,
                           unsigned short* __restrict__ wpk1, unsigned short* __restrict__ wpk2,
                           unsigned short* __restrict__ wpk3, unsigned short* __restrict__ wpk4,
                           float* __restrict__ sums)
{
    int i = blockIdx.x * 256 + threadIdx.x;
    if (i < 4 * 6 * 64 * 2 * NREP) sums[i] = 0.f;   // zero all 4 stages' stat sums
    if (i < 3 * 36864) {
        int set = i / 36864, ii = i - set * 36864;
        const float* w = (set == 0) ? w2 : (set == 1) ? w3 : w4;
        unsigned short* wpk = (set == 0) ? wpk2 : (set == 1) ? wpk3 : wpk4;
        int j = ii & 7, lane = (ii >> 3) & 63, chunk = ii >> 9;
        int nt = chunk & 3, half = (chunk >> 2) & 1, t = chunk >> 3;
        int co = nt * 16 + (lane & 15);
        int ci = half * 32 + (lane >> 4) * 8 + j;
        wpk[ii] = bf16bits(w[co * 576 + ci * 9 + t]);
    } else {
        int ii = i - 3 * 36864;
        if (ii >= 4096) return;
        int j = ii & 7, lane = (ii >> 3) & 63, c8 = ii >> 9;
        int nt = c8 & 3, f = c8 >> 2;
        int co = nt * 16 + (lane & 15), q = lane >> 4;
        int k = q * 8 + j;
        float val = 0.f;
        if (f == 0) {
            int t = k >> 2, ci = k & 3;
            if (ci < 3) val = w1[co * 27 + ci * 9 + t];
        } else if (k < 4) {
            int ci = k & 3;
            if (ci < 3) val = w1[co * 27 + ci * 9 + 8];
        }
        wpk1[ii] = bf16bits(val);
    }
}

// ------- MFMA conv1 3->64, fused BN stats + FULL 2x2 maxpool (x in regs, y via LDS) -------
// maxpool commutes with BN1+LReLU (a = gamma/std > 0, both monotonic), so conv1 pools RAW
// conv outputs and conv2 applies BN+LReLU on the pooled tensor. One block = one row-pair
// (2 image rows = 168 pixels); output [42][42][64] per image (6.4MB total vs 25.7MB before).
// BN1 stats still accumulate over raw pre-pool values (reference semantics).
__global__ __launch_bounds__(256) void conv1m_k(const float* __restrict__ in1,
                                                const float* __restrict__ in2,
                                                const unsigned short* __restrict__ wpk1,
                                                __hip_bfloat16* __restrict__ xpool,
                                                float* __restrict__ sums)
{
    constexpr int S = 84, P = P1, MB = 168, SPAN = MB + 2 * S + 2;   // 338 staged pixels
    __shared__ __align__(16) unsigned short ls4[384 * 4];   // 8 B per pixel [c0,c1,c2,0]
    __shared__ float xmx[2 * 42 * 64];                      // x-maxed raw, 2 rows
    __shared__ float qs[4][64], qs2[4][64];
    int img = blockIdx.x / 42;
    int rp = blockIdx.x % 42;              // row-pair index: rows 2*rp, 2*rp+1
    int p0 = rp * MB;
    int tid = threadIdx.x, lane = tid & 63, wv = tid >> 6;
    int col = lane & 15, quad = lane >> 4;
    const float* in = (img < NQ) ? in1 + (size_t)img * 3 * P1
                                 : in2 + (size_t)(img - NQ) * 3 * P1;
    for (int u = tid; u < SPAN; u += 256) {
        int p = p0 - S - 1 + u;
        union { unsigned short us[4]; uint2 u2; } o;
        o.u2 = (uint2){0u, 0u};
        if (p >= 0 && p < P) {
            o.us[0] = bf16bits(in[p]);
            o.us[1] = bf16bits(in[P1 + p]);
            o.us[2] = bf16bits(in[2 * P1 + p]);
        }
        *(uint2*)(ls4 + u * 4) = o.u2;
    }
    const short8* wb = (const short8*)wpk1;
    short8 b0[4], b1[4];
    #pragma unroll
    for (int nt = 0; nt < 4; ++nt) {
        b0[nt] = wb[(size_t)(nt * 64 + lane)];
        b1[nt] = wb[(size_t)((4 + nt) * 64 + lane)];
    }
    int t0 = 2 * quad, t1 = t0 + 1;
    int d0 = (t0 / 3 - 1) * S + (t0 % 3 - 1);
    int d1 = (t1 / 3 - 1) * S + (t1 % 3 - 1);
    const int d8 = S + 1;
    int tx0 = t0 % 3, tx1 = t1 % 3;
    __syncthreads();
    f32x4 acc[3][4];
    #pragma unroll
    for (int mt = 0; mt < 3; ++mt)
        #pragma unroll
        for (int nt = 0; nt < 4; ++nt) acc[mt][nt] = (f32x4){0.f, 0.f, 0.f, 0.f};
    #pragma unroll
    for (int mt = 0; mt < 3; ++mt) {
        int pl = wv * 48 + mt * 16 + col;  // 0..191 (pl>=168 lanes masked downstream)
        int xm = pl % S;                   // p0 % 84 == 0
        int base = pl + S + 1;             // max read base+d8 = 191+170 = 361 < 384
        uint2 h0 = *(const uint2*)(ls4 + (base + d0) * 4);
        uint2 h1 = *(const uint2*)(ls4 + (base + d1) * 4);
        uint2 h8 = *(const uint2*)(ls4 + (base + d8) * 4);
        bool ok0 = (tx0 == 0) ? (xm >= 1) : ((tx0 == 2) ? (xm <= S - 2) : true);
        bool ok1 = (tx1 == 0) ? (xm >= 1) : ((tx1 == 2) ? (xm <= S - 2) : true);
        bool ok8 = (quad == 0) && (xm <= S - 2);
        if (!ok0) h0 = (uint2){0u, 0u};
        if (!ok1) h1 = (uint2){0u, 0u};
        if (!ok8) h8 = (uint2){0u, 0u};
        union { uint4 u; short8 s; } ca, cb;
        ca.u = (uint4){h0.x, h0.y, h1.x, h1.y};
        cb.u = (uint4){h8.x, h8.y, 0u, 0u};
        #pragma unroll
        for (int nt = 0; nt < 4; ++nt) {
            acc[mt][nt] = __builtin_amdgcn_mfma_f32_16x16x32_bf16(ca.s, b0[nt], acc[mt][nt], 0, 0, 0);
            acc[mt][nt] = __builtin_amdgcn_mfma_f32_16x16x32_bf16(cb.s, b1[nt], acc[mt][nt], 0, 0, 0);
        }
    }
    float s[4] = {0.f, 0.f, 0.f, 0.f}, s2[4] = {0.f, 0.f, 0.f, 0.f};
    #pragma unroll
    for (int mt = 0; mt < 3; ++mt) {
        int tb = wv * 48 + mt * 16 + quad * 4;      // local pixel base for this lane's regs
        #pragma unroll
        for (int reg = 0; reg < 4; ++reg) {
            int pr = tb + reg;
            if (pr < MB) {                 // stats over raw (pre-pool) values
                #pragma unroll
                for (int nt = 0; nt < 4; ++nt) {
                    float v = acc[mt][nt][reg];
                    s[nt] += v;
                    s2[nt] = fmaf(v, v, s2[nt]);
                }
            }
        }
        #pragma unroll
        for (int pr2 = 0; pr2 < 2; ++pr2) {         // x-pair max -> LDS
            int m0 = tb + pr2 * 2;
            if (m0 < MB) {
                int r = (m0 >= S) ? 1 : 0;
                int xo = (m0 - r * S) >> 1;
                #pragma unroll
                for (int nt = 0; nt < 4; ++nt) {
                    float v = fmaxf(acc[mt][nt][pr2 * 2], acc[mt][nt][pr2 * 2 + 1]);
                    xmx[(r * 42 + xo) * 64 + nt * 16 + col] = v;
                }
            }
        }
    }
    __syncthreads();
    // y-pair max + coalesced bf16 store of the fully pooled row
    __hip_bfloat16* ob = xpool + (size_t)img * P2 * 64;
    for (int i = tid; i < 42 * 64; i += 256) {
        int xo = i >> 6, ch = i & 63;
        float v = fmaxf(xmx[xo * 64 + ch], xmx[(42 + xo) * 64 + ch]);
        ob[((size_t)(rp * 42 + xo)) * 64 + ch] = __float2bfloat16(v);
    }
    #pragma unroll
    for (int d = 16; d < 64; d <<= 1)
        #pragma unroll
        for (int nt = 0; nt < 4; ++nt) {
            s[nt] += __shfl_xor(s[nt], d, 64);
            s2[nt] += __shfl_xor(s2[nt], d, 64);
        }
    if (quad == 0) {
        #pragma unroll
        for (int nt = 0; nt < 4; ++nt) {
            qs[wv][nt * 16 + col] = s[nt];
            qs2[wv][nt * 16 + col] = s2[nt];
        }
    }
    __syncthreads();
    if (wv == 0) {
        int g = (img < NQ) ? 0 : 1 + (img - NQ) / SHOT;
        int rep = blockIdx.x & (NREP - 1);
        float ts = qs[0][lane] + qs[1][lane] + qs[2][lane] + qs[3][lane];
        float ts2 = qs2[0][lane] + qs2[1][lane] + qs2[2][lane] + qs2[3][lane];
        float* base = sums + ((size_t)(g * 64 + lane) * 2) * NREP + rep;
        atomicAdd(base, ts);
        atomicAdd(base + NREP, ts2);
    }
}

// block-level BN finalize: reduce prev-stage sums (64ch x 2 x NREP) -> LDS (a,b) pairs.
template <int PREVP>
__device__ __forceinline__ void bn_fold(const float* __restrict__ sums_prev,
                                        const float* __restrict__ gamma,
                                        const float* __restrict__ beta,
                                        int g, int tid, float* msl)
{
    if (tid < 64) {
        const float* ps = sums_prev + (size_t)(g * 64 + tid) * 2 * NREP;
        float s = 0.f, s2 = 0.f;
        #pragma unroll
        for (int r = 0; r < NREP; ++r) { s += ps[r]; s2 += ps[NREP + r]; }
        float cnt = (float)((g == 0 ? NQ : SHOT) * PREVP);
        float mean = s / cnt;
        float var = s2 / cnt - mean * mean;
        float a = rsqrtf(var + EPSB) * gamma[tid];
        msl[tid * 2] = a;
        msl[tid * 2 + 1] = fmaf(-mean, a, beta[tid]);
    }
}

// ------- MFMA conv 64->64. Staging MODE: 1 = BN+LReLU on bf16 raw;
//         2 = y-pair max on x-pooled raw [2S x S] + BN + LReLU (fused bnpooly).
//         BN fold (prev-stage stats) computed per block in the prologue.
//         Output raw bf16; POOLX adds in-register x-pair max (out [P/2]).
template <int S, int MBLK, int MODE, bool POOLX, int PREVP>
__global__ __launch_bounds__(256) void conv64m_k(const unsigned short* __restrict__ inv,
                                                 const unsigned short* __restrict__ wpk,
                                                 __hip_bfloat16* __restrict__ out,
                                                 float* __restrict__ sums,
                                                 const float* __restrict__ sums_prev,
                                                 const float* __restrict__ gamma,
                                                 const float* __restrict__ beta)
{
    constexpr int P = S * S;
    constexpr int MT = MBLK / 64;
    constexpr int NB = (P + MBLK - 1) / MBLK;
    constexpr int SPAN = MBLK + 2 * S + 2;
    __shared__ __align__(16) unsigned short ls[SPAN * 72];
    __shared__ float qs[4][64], qs2[4][64];
    __shared__ float msl[128];
    int img = blockIdx.x / NB;
    int p0 = (blockIdx.x % NB) * MBLK;
    int tid = threadIdx.x;
    int lane = tid & 63, wv = tid >> 6;
    int col = lane & 15, quad = lane >> 4;
    int g = (img < NQ) ? 0 : 1 + (img - NQ) / SHOT;
    bn_fold<PREVP>(sums_prev, gamma, beta, g, tid, msl);
    __syncthreads();
    {
        int part = tid & 7;
        float ba[8], bb[8];
        #pragma unroll
        for (int j = 0; j < 8; ++j) {
            ba[j] = msl[(part * 8 + j) * 2];
            bb[j] = msl[(part * 8 + j) * 2 + 1];
        }
        if constexpr (MODE == 1) {
            const unsigned short* ib = inv + (size_t)img * P * 64;
            for (int u = tid; u < SPAN * 8; u += 256) {
                int pix = u >> 3;
                int p = p0 - S - 1 + pix;
                union { unsigned short us[8]; short8 s8; } o;
                #pragma unroll
                for (int j = 0; j < 8; ++j) o.us[j] = 0;
                if (p >= 0 && p < P) {
                    union { short8 s8; unsigned short us[8]; } x;
                    x.s8 = *(const short8*)(ib + (size_t)p * 64 + part * 8);
                    #pragma unroll
                    for (int j = 0; j < 8; ++j) {
                        float v = fmaf(bits2f(x.us[j]), ba[j], bb[j]);
                        v = fmaxf(v, SLOPE * v);
                        o.us[j] = bf16bits(v);
                    }
                }
                *(short8*)(ls + pix * 72 + part * 8) = o.s8;
            }
        } else {
            // MODE 2: input is x-pooled raw of previous conv: [2S rows][S wide], 64ch
            const unsigned short* ib2 = inv + (size_t)img * (2 * (size_t)P) * 64;
            for (int u = tid; u < SPAN * 8; u += 256) {
                int pix = u >> 3;
                int p = p0 - S - 1 + pix;
                union { unsigned short us[8]; short8 s8; } o;
                #pragma unroll
                for (int j = 0; j < 8; ++j) o.us[j] = 0;
                if (p >= 0 && p < P) {
                    int y = p / S, x = p - y * S;
                    const unsigned short* src = ib2 + ((size_t)(2 * y) * S + x) * 64 + part * 8;
                    union { short8 s8; unsigned short us[8]; } x0, x1;
                    x0.s8 = *(const short8*)src;
                    x1.s8 = *(const short8*)(src + (size_t)S * 64);
                    #pragma unroll
                    for (int j = 0; j < 8; ++j) {
                        float v = fmaxf(bits2f(x0.us[j]), bits2f(x1.us[j]));
                        v = fmaf(v, ba[j], bb[j]);
                        v = fmaxf(v, SLOPE * v);
                        o.us[j] = bf16bits(v);
                    }
                }
                *(short8*)(ls + pix * 72 + part * 8) = o.s8;
            }
        }
    }
    __syncthreads();
    f32x4 acc[MT][4];
    #pragma unroll
    for (int mt = 0; mt < MT; ++mt)
        #pragma unroll
        for (int nt = 0; nt < 4; ++nt) acc[mt][nt] = (f32x4){0.f, 0.f, 0.f, 0.f};
    bool mok0[MT], mok2[MT];
    #pragma unroll
    for (int mt = 0; mt < MT; ++mt) {
        int xm = (p0 + wv * (MT * 16) + mt * 16 + col) % S;
        mok0[mt] = xm >= 1;
        mok2[mt] = xm <= S - 2;
    }
    const short8* wb = (const short8*)wpk;
    #pragma unroll
    for (int ky = 0; ky < 3; ++ky) {
        #pragma unroll
        for (int kx = 0; kx < 3; ++kx) {
            int t = ky * 3 + kx;
            int d = (ky - 1) * S + (kx - 1);
            #pragma unroll
            for (int half = 0; half < 2; ++half) {
                short8 b[4];
                #pragma unroll
                for (int nt = 0; nt < 4; ++nt)
                    b[nt] = wb[((t * 2 + half) * 4 + nt) * 64 + lane];
                #pragma unroll
                for (int mt = 0; mt < MT; ++mt) {
                    int idx = wv * (MT * 16) + mt * 16 + col + S + 1 + d;
                    short8 a = *(const short8*)(ls + idx * 72 + half * 32 + quad * 8);
                    bool ok = (kx == 0) ? mok0[mt] : (kx == 2) ? mok2[mt] : true;
                    if (!ok) a = (short8){0, 0, 0, 0, 0, 0, 0, 0};
                    #pragma unroll
                    for (int nt = 0; nt < 4; ++nt)
                        acc[mt][nt] = __builtin_amdgcn_mfma_f32_16x16x32_bf16(a, b[nt], acc[mt][nt], 0, 0, 0);
                }
            }
        }
    }
    float s[4] = {0.f, 0.f, 0.f, 0.f}, s2[4] = {0.f, 0.f, 0.f, 0.f};
    __hip_bfloat16* ob = out + (size_t)img * (POOLX ? P / 2 : P) * 64;
    #pragma unroll
    for (int mt = 0; mt < MT; ++mt) {
        int tb = p0 + wv * (MT * 16) + mt * 16 + quad * 4;
        #pragma unroll
        for (int reg = 0; reg < 4; ++reg) {
            int pr = tb + reg;
            if (pr < P) {
                #pragma unroll
                for (int nt = 0; nt < 4; ++nt) {
                    float v = acc[mt][nt][reg];
                    s[nt] += v;
                    s2[nt] = fmaf(v, v, s2[nt]);
                }
            }
        }
        if constexpr (POOLX) {
            #pragma unroll
            for (int pr2 = 0; pr2 < 2; ++pr2) {
                int m0 = tb + pr2 * 2;
                if (m0 < P) {
                    #pragma unroll
                    for (int nt = 0; nt < 4; ++nt) {
                        float v = fmaxf(acc[mt][nt][pr2 * 2], acc[mt][nt][pr2 * 2 + 1]);
                        ob[(size_t)(m0 >> 1) * 64 + nt * 16 + col] = __float2bfloat16(v);
                    }
                }
            }
        } else {
            #pragma unroll
            for (int reg = 0; reg < 4; ++reg) {
                int pr = tb + reg;
                if (pr < P) {
                    #pragma unroll
                    for (int nt = 0; nt < 4; ++nt)
                        ob[(size_t)pr * 64 + nt * 16 + col] = __float2bfloat16(acc[mt][nt][reg]);
                }
            }
        }
    }
    #pragma unroll
    for (int d = 16; d < 64; d <<= 1)
        #pragma unroll
        for (int nt = 0; nt < 4; ++nt) {
            s[nt] += __shfl_xor(s[nt], d, 64);
            s2[nt] += __shfl_xor(s2[nt], d, 64);
        }
    if (quad == 0) {
        #pragma unroll
        for (int nt = 0; nt < 4; ++nt) {
            qs[wv][nt * 16 + col] = s[nt];
            qs2[wv][nt * 16 + col] = s2[nt];
        }
    }
    __syncthreads();
    if (wv == 0) {
        int rep = blockIdx.x & (NREP - 1);
        float ts = qs[0][lane] + qs[1][lane] + qs[2][lane] + qs[3][lane];
        float ts2 = qs2[0][lane] + qs2[1][lane] + qs2[2][lane] + qs2[3][lane];
        float* base = sums + ((size_t)(g * 64 + lane) * 2) * NREP + rep;
        atomicAdd(base, ts);
        atomicAdd(base + NREP, ts2);
    }
}

// ---- BN4 fold + BN + LeakyReLU + per-pixel L2-normalize, 32 pixels/block ----
__global__ __launch_bounds__(256) void bnnorm_k(const unsigned short* __restrict__ x,
                                                const float* __restrict__ sums_prev,
                                                const float* __restrict__ g4,
                                                const float* __restrict__ b4,
                                                __hip_bfloat16* __restrict__ out)
{
    __shared__ float msl[2][128];          // group-specific fold: both groups computed
    int tid = threadIdx.x;
    int pix0 = blockIdx.x * BNPIX;
    int imgA = pix0 / P3;
    int plast = pix0 + BNPIX - 1; if (plast >= NIMG * P3) plast = NIMG * P3 - 1;
    int imgB = plast / P3;
    int ga = (imgA < NQ) ? 0 : 1 + (imgA - NQ) / SHOT;
    int gb = (imgB < NQ) ? 0 : 1 + (imgB - NQ) / SHOT;
    bn_fold<P3>(sums_prev, g4, b4, ga, tid, msl[0]);
    if (gb != ga) bn_fold<P3>(sums_prev, g4, b4, gb, tid, msl[1]);
    __syncthreads();
    int lane = tid & 63, wvr = tid >> 6;
    int pbase = pix0 + wvr * 8;            // 8 pixels per wave
    float v[8];
    #pragma unroll
    for (int i = 0; i < 8; ++i) {          // independent loads first (MLP)
        int pix = pbase + i;
        v[i] = (pix < NIMG * P3) ? bits2f(x[(size_t)pix * 64 + lane]) : 0.f;
    }
    #pragma unroll
    for (int i = 0; i < 8; ++i) {
        int pix = pbase + i;
        if (pix >= NIMG * P3) break;       // wave-uniform
        int img = pix / P3;
        int g = (img < NQ) ? 0 : 1 + (img - NQ) / SHOT;
        const float* ms = msl[(g == ga) ? 0 : 1];
        float w = fmaf(v[i], ms[lane * 2], ms[lane * 2 + 1]);
        w = w >= 0.f ? w : SLOPE * w;
        float ss = w * w;
        #pragma unroll
        for (int d = 32; d > 0; d >>= 1) ss += __shfl_xor(ss, d, 64);
        out[(size_t)pix * 64 + lane] = __float2bfloat16(w * rsqrtf(ss));
    }
}

// ---------------- similarity: m-split blocks, dbuf LDS chunks, partial top-3 + merge -------
// (exact R7/R10 version: dbuf, one barrier/chunk -- 49.8us proven)
__device__ __forceinline__ void ins3(float v, float& t0, float& t1, float& t2)
{
    t2 = __builtin_amdgcn_fmed3f(v, t1, t2);
    t1 = __builtin_amdgcn_fmed3f(v, t0, t1);
    t0 = fmaxf(t0, v);
}

// merge lane^xor partner's sorted top-3 via ds_swizzle (BitMode: (xor<<10)|0x1F)
template <int PAT>
__device__ __forceinline__ void swzmerge(float& t0, float& t1, float& t2)
{
    float u0 = __int_as_float(__builtin_amdgcn_ds_swizzle(__float_as_int(t0), PAT));
    float u1 = __int_as_float(__builtin_amdgcn_ds_swizzle(__float_as_int(t1), PAT));
    float u2 = __int_as_float(__builtin_amdgcn_ds_swizzle(__float_as_int(t2), PAT));
    ins3(u0, t0, t1, t2);
    ins3(u1, t0, t1, t2);
    ins3(u2, t0, t1, t2);
}

// grid: bq(32) x n(5) x qb(4) x mr(2) = 1280 blocks.
__global__ __launch_bounds__(256) void sim_part_k(const __hip_bfloat16* __restrict__ fhat,
                                                  float* __restrict__ part)
{
    __shared__ __align__(16) unsigned short sl[2][64 * SLS];
    int t = blockIdx.x;
    int mr = t & 1;
    int qb = (t >> 1) & 3;
    int n = (t >> 3) % NCLS;
    int bq = t / (8 * NCLS);
    int tid = threadIdx.x, lane = tid & 63, wv = tid >> 6;
    int col = lane & 15, quad = lane >> 4;
    short8 a0[QG], a1[QG];
    #pragma unroll
    for (int g = 0; g < QG; ++g) {
        int q = qb * QBLK + wv * (QG * 16) + g * 16 + col;
        int qc = q < P3 ? q : P3 - 1;
        const unsigned short* qp = (const unsigned short*)fhat + ((size_t)bq * P3 + qc) * 64;
        a0[g] = *(const short8*)(qp + quad * 8);
        a1[g] = *(const short8*)(qp + 32 + quad * 8);
    }
    const unsigned short* sp = (const unsigned short*)fhat + (size_t)(NQ + n * SHOT) * P3 * 64;
    int m_lo = mr * MSPAN;
    int m_cnt = MM - m_lo; if (m_cnt > MSPAN) m_cnt = MSPAN;
    int nfull = m_cnt >> 6;                // 18, 16
    int rem = m_cnt & 63;                  // 0, 29   (rem < 32 always)
    float t0[QG][4], t1[QG][4], t2[QG][4];
    #pragma unroll
    for (int g = 0; g < QG; ++g)
        #pragma unroll
        for (int r = 0; r < 4; ++r) { t0[g][r] = NEGINF; t1[g][r] = NEGINF; t2[g][r] = NEGINF; }
    int srow = tid >> 3, scc = (tid & 7) * 8;
    const unsigned short* gp = sp + (size_t)(m_lo + srow) * 64 + scc;
    unsigned short* ld0 = &sl[0][srow * SLS + scc];
    unsigned short* ld1 = &sl[1][srow * SLS + scc];
    const short8 z8 = {0, 0, 0, 0, 0, 0, 0, 0};
    // prologue: chunk 0 is always full
    short8 v0 = *(const short8*)gp;
    short8 v1 = *(const short8*)(gp + 32 * 64);
    *(short8*)ld0 = v0;
    *(short8*)(ld0 + 32 * SLS) = v1;
    __syncthreads();
    int cur = 0;
    for (int c = 0; c < nfull; ++c) {
        bool nf = (c + 1 < nfull);
        bool np = (c + 1 == nfull) && (rem != 0);
        if (nf) {                          // issue next full chunk's loads early
            gp += 64 * 64;
            v0 = *(const short8*)gp;
            v1 = *(const short8*)(gp + 32 * 64);
        } else if (np) {                   // partial chunk's loads (rem<32: v1 all zero)
            gp += 64 * 64;
            v0 = (srow < rem) ? *(const short8*)gp : z8;
            v1 = z8;
        }
        const unsigned short* sr = &sl[cur][col * SLS + quad * 8];
        #pragma unroll
        for (int mt = 0; mt < 4; ++mt) {   // branch-free: full chunk, all tiles valid
            short8 b0 = *(const short8*)(sr + mt * (16 * SLS));
            short8 b1 = *(const short8*)(sr + mt * (16 * SLS) + 32);
            #pragma unroll
            for (int g = 0; g < QG; ++g) {
                f32x4 acc = {0.f, 0.f, 0.f, 0.f};
                acc = __builtin_amdgcn_mfma_f32_16x16x32_bf16(a0[g], b0, acc, 0, 0, 0);
                acc = __builtin_amdgcn_mfma_f32_16x16x32_bf16(a1[g], b1, acc, 0, 0, 0);
                #pragma unroll
                for (int r = 0; r < 4; ++r) ins3(acc[r], t0[g][r], t1[g][r], t2[g][r]);
            }
        }
        if (nf | np) {                     // write next chunk into the other buffer
            unsigned short* ld = (cur == 0) ? ld1 : ld0;
            *(short8*)ld = v0;
            *(short8*)(ld + 32 * SLS) = v1;
        }
        __syncthreads();
        cur ^= 1;
    }
    if (rem) {                             // peeled partial chunk (mr=1 only): mask fake rows
        const unsigned short* sr = &sl[cur][col * SLS + quad * 8];
        int ptiles = (rem + 15) >> 4;      // 2
        for (int mt = 0; mt < ptiles; ++mt) {
            short8 b0 = *(const short8*)(sr + mt * (16 * SLS));
            short8 b1 = *(const short8*)(sr + mt * (16 * SLS) + 32);
            bool valid = (mt * 16 + col) < rem;
            #pragma unroll
            for (int g = 0; g < QG; ++g) {
                f32x4 acc = {0.f, 0.f, 0.f, 0.f};
                acc = __builtin_amdgcn_mfma_f32_16x16x32_bf16(a0[g], b0, acc, 0, 0, 0);
                acc = __builtin_amdgcn_mfma_f32_16x16x32_bf16(a1[g], b1, acc, 0, 0, 0);
                #pragma unroll
                for (int r = 0; r < 4; ++r)
                    ins3(valid ? acc[r] : NEGINF, t0[g][r], t1[g][r], t2[g][r]);
            }
        }
    }
    // butterfly merge across the 16 cols (m residues) via ds_swizzle
    #pragma unroll
    for (int g = 0; g < QG; ++g)
        #pragma unroll
        for (int r = 0; r < 4; ++r) {
            swzmerge<0x041F>(t0[g][r], t1[g][r], t2[g][r]);
            swzmerge<0x081F>(t0[g][r], t1[g][r], t2[g][r]);
            swzmerge<0x101F>(t0[g][r], t1[g][r], t2[g][r]);
            swzmerge<0x201F>(t0[g][r], t1[g][r], t2[g][r]);
        }
    if (col == 0) {
        #pragma unroll
        for (int g = 0; g < QG; ++g)
            #pragma unroll
            for (int r = 0; r < 4; ++r) {
                int ql = wv * (QG * 16) + g * 16 + quad * 4 + r;
                float* pp = part + ((((size_t)(bq * NCLS + n) * NQB + qb) * MRNG + mr) * QBLK + ql) * 3;
                pp[0] = t0[g][r];
                pp[1] = t1[g][r];
                pp[2] = t2[g][r];
            }
    }
}

// one block per (bq, n): merge 2 m-range partials per q, sum top-3, write out directly
__global__ __launch_bounds__(256) void sim_merge_k(const float* __restrict__ part,
                                                   float* __restrict__ out)
{
    __shared__ float red[4];
    int b = blockIdx.x;                    // bq*NCLS + n
    int tid = threadIdx.x, lane = tid & 63, wv = tid >> 6;
    float s = 0.f;
    for (int q = tid; q < P3; q += 256) {
        int qb = q >> 7, ql = q & 127;
        const float* pp = part + (((size_t)b * NQB + qb) * MRNG * QBLK + ql) * 3;
        float v0 = pp[0], v1 = pp[1], v2 = pp[2];
        #pragma unroll
        for (int mr = 1; mr < MRNG; ++mr) {
            const float* pm = pp + (size_t)mr * (QBLK * 3);
            ins3(pm[0], v0, v1, v2);
            ins3(pm[1], v0, v1, v2);
            ins3(pm[2], v0, v1, v2);
        }
        s += v0 + v1 + v2;
    }
    #pragma unroll
    for (int d = 32; d > 0; d >>= 1) s += __shfl_xor(s, d, 64);
    if (lane == 0) red[wv] = s;
    __syncthreads();
    if (tid == 0) out[b] = red[0] + red[1] + red[2] + red[3];
}

extern "C" void kernel_launch(void* const* d_in, const int* in_sizes, int n_in,
                              void* d_out, int out_size, void* d_ws, size_t ws_size,
                              hipStream_t stream)
{
    const float* input1 = (const float*)d_in[0];
    const float* input2 = (const float*)d_in[1];
    const float* w1 = (const float*)d_in[2];
    const float* g1 = (const float*)d_in[3];
    const float* b1 = (const float*)d_in[4];
    const float* w2 = (const float*)d_in[5];
    const float* g2 = (const float*)d_in[6];
    const float* b2 = (const float*)d_in[7];
    const float* w3 = (const float*)d_in[8];
    const float* g3 = (const float*)d_in[9];
    const float* b3 = (const float*)d_in[10];
    const float* w4 = (const float*)d_in[11];
    const float* g4 = (const float*)d_in[12];
    const float* b4 = (const float*)d_in[13];
    float* out = (float*)d_out;

    char* w8 = (char*)d_ws;
    const size_t oB = 51480576;
    const size_t oT = oB + 12870144;
    const size_t STG = 6 * 64 * 2 * NREP * sizeof(float);   // 98304 B per stage
    __hip_bfloat16* xpool1 = (__hip_bfloat16*)(w8 + 0);     // [57][1764][64] bf16 12.9MB (fully pooled)
    __hip_bfloat16* conv3raw = (__hip_bfloat16*)(w8 + 0);   // reuse A: [57][441][64] bf16 3.2MB
    __hip_bfloat16* conv4raw = (__hip_bfloat16*)(w8 + 9652608);  // 3.2MB bf16
    __hip_bfloat16* fhat = (__hip_bfloat16*)(w8 + 16087680);
    __hip_bfloat16* xpool2 = (__hip_bfloat16*)(w8 + oB);    // [57][882][64] bf16 6.44MB
    float* sums = (float*)(w8 + oT);                        // 4 stages x 98304 B
    unsigned short* wpk2 = (unsigned short*)(w8 + oT + 4 * STG + 12288);
    unsigned short* wpk3 = (unsigned short*)(w8 + oT + 4 * STG + 12288 + 73728);
    unsigned short* wpk4 = (unsigned short*)(w8 + oT + 4 * STG + 12288 + 147456);
    unsigned short* wpk1 = (unsigned short*)(w8 + oT + 4 * STG + 12288 + 221184);
    const size_t oP = oT + 4 * STG + 12288 + 221184 + 8192;
    float* part = (float*)(w8 + oP);                        // 32*5*4*2*128*3 f32 = 1.97MB
    if (ws_size < oP + (size_t)NQ * NCLS * NQB * MRNG * QBLK * 3 * sizeof(float)) return;
    float* sums1 = sums;
    float* sums2 = sums + 6 * 64 * 2 * NREP;
    float* sums3 = sums2 + 6 * 64 * 2 * NREP;
    float* sums4 = sums3 + 6 * 64 * 2 * NREP;

    // pack weights + zero stats (no memsets needed; sim_merge overwrites all of d_out)
    pack_all_k<<<448, 256, 0, stream>>>(w1, w2, w3, w4, wpk1, wpk2, wpk3, wpk4, sums);

    // stage 1: conv1 MFMA + full 2x2 pool of raw outputs (+raw stats); one block per row-pair
    conv1m_k<<<NIMG * 42, 256, 0, stream>>>(input1, input2, wpk1, xpool1, sums1);
    // stage 2: conv2 on the pooled tensor, BN1+LReLU in MODE-1 staging, x-pool epilogue
    conv64m_k<42, 128, 1, true, P1><<<NIMG * 14, 256, 0, stream>>>(
        (const unsigned short*)xpool1, wpk2, xpool2, sums2, sums1, g1, b1);
    // stage 3: conv3, BN2 folded; MBLK=64 (MT=1): 399 blocks
    conv64m_k<21, 64, 2, false, P2><<<NIMG * 7, 256, 0, stream>>>(
        (const unsigned short*)xpool2, wpk3, conv3raw, sums3, sums2, g2, b2);
    // stage 4: conv4, BN3 folded; MBLK=64 (MT=1): 399 blocks
    conv64m_k<21, 64, 1, false, P3><<<NIMG * 7, 256, 0, stream>>>(
        (const unsigned short*)conv3raw, wpk4, conv4raw, sums4, sums3, g3, b3);
    // BN4 fold + BN + LReLU + L2-normalize (32 pixels/block)
    bnnorm_k<<<(NIMG * P3 + BNPIX - 1) / BNPIX, 256, 0, stream>>>(
        (const unsigned short*)conv4raw, sums4, g4, b4, fhat);
    // similarity: partial top-3 over m-ranges, then merge (writes d_out directly)
    sim_part_k<<<NQ * NCLS * NQB * MRNG, 256, 0, stream>>>(fhat, part);
    sim_merge_k<<<NQ * NCLS, 256, 0, stream>>>(part, out);
}

// Round 12
// 211.884 us; speedup vs baseline: 1.0272x; 1.0272x over previous
//
#include <hip/hip_runtime.h>
#include <hip/hip_bf16.h>
#include <stdint.h>

#define NQ 32
#define NCLS 5
#define SHOT 5
#define NIMG 57          // 32 query + 25 support
#define P1 7056          // 84*84
#define P2 1764          // 42*42
#define P3 441           // 21*21
#define PX 3528          // x-pooled stage-1 grid: 84 rows x 42
#define MM (SHOT*P3)     // 2205
#define EPSB 1e-5f
#define SLOPE 0.2f
#define NEGINF -3.4e38f
#define NREP 32          // stats atomic replication factor
#define MSPAN 1152       // sim m-range rows per block (mr=0: 18 full; mr=1: 16 full + 29)
#define MRNG 2           // m-ranges (2*1152 >= 2205) -> 1280 blocks
#define QBLK 128         // sim q rows per block (2 groups of 16 per wave)
#define NQB 4            // ceil(441/128)
#define QG 2             // q-groups per wave (QG=4 @112 VGPR killed TLP; gate added issue: both reverted)
#define SLS 72           // sim LDS row stride in ushorts
#define BNPIX 32         // bnnorm pixels per block

typedef __attribute__((ext_vector_type(8))) short short8;
typedef __attribute__((ext_vector_type(4))) float f32x4;

__device__ __forceinline__ unsigned short bf16bits(float v)
{
    __hip_bfloat16 h = __float2bfloat16(v);
    return *reinterpret_cast<unsigned short*>(&h);
}
__device__ __forceinline__ float bits2f(unsigned short u)
{
    unsigned int x = ((unsigned int)u) << 16;
    return *reinterpret_cast<float*>(&x);
}

// ---------------- all weight packs + zero stats sums, one launch ----------------
__global__ void pack_all_k(const float* __restrict__ w1, const float* __restrict__ w2,
                           const float* __restrict__ w3, const float* __restrict__ w4,
                           unsigned short* __restrict__ wpk1, unsigned short* __restrict__ wpk2,
                           unsigned short* __restrict__ wpk3, unsigned short* __restrict__ wpk4,
                           float* __restrict__ sums)
{
    int i = blockIdx.x * 256 + threadIdx.x;
    if (i < 4 * 6 * 64 * 2 * NREP) sums[i] = 0.f;   // zero all 4 stages' stat sums
    if (i < 3 * 36864) {
        int set = i / 36864, ii = i - set * 36864;
        const float* w = (set == 0) ? w2 : (set == 1) ? w3 : w4;
        unsigned short* wpk = (set == 0) ? wpk2 : (set == 1) ? wpk3 : wpk4;
        int j = ii & 7, lane = (ii >> 3) & 63, chunk = ii >> 9;
        int nt = chunk & 3, half = (chunk >> 2) & 1, t = chunk >> 3;
        int co = nt * 16 + (lane & 15);
        int ci = half * 32 + (lane >> 4) * 8 + j;
        wpk[ii] = bf16bits(w[co * 576 + ci * 9 + t]);
    } else {
        int ii = i - 3 * 36864;
        if (ii >= 4096) return;
        int j = ii & 7, lane = (ii >> 3) & 63, c8 = ii >> 9;
        int nt = c8 & 3, f = c8 >> 2;
        int co = nt * 16 + (lane & 15), q = lane >> 4;
        int k = q * 8 + j;
        float val = 0.f;
        if (f == 0) {
            int t = k >> 2, ci = k & 3;
            if (ci < 3) val = w1[co * 27 + ci * 9 + t];
        } else if (k < 4) {
            int ci = k & 3;
            if (ci < 3) val = w1[co * 27 + ci * 9 + 8];
        }
        wpk1[ii] = bf16bits(val);
    }
}

// ---------------- MFMA conv1 3->64, fused BN stats + in-register x-pair max ----------------
__global__ __launch_bounds__(256) void conv1m_k(const float* __restrict__ in1,
                                                const float* __restrict__ in2,
                                                const unsigned short* __restrict__ wpk1,
                                                __hip_bfloat16* __restrict__ xpool,
                                                float* __restrict__ sums)
{
    constexpr int S = 84, P = P1, MBLK = 256, NB = 28, SPAN = MBLK + 2 * S + 2;  // 426
    __shared__ __align__(16) unsigned short ls4[SPAN * 4];   // 8 B per pixel [c0,c1,c2,0]
    __shared__ float qs[4][64], qs2[4][64];
    int img = blockIdx.x / NB;
    int p0 = (blockIdx.x % NB) * MBLK;
    int tid = threadIdx.x, lane = tid & 63, wv = tid >> 6;
    int col = lane & 15, quad = lane >> 4;
    const float* in = (img < NQ) ? in1 + (size_t)img * 3 * P1
                                 : in2 + (size_t)(img - NQ) * 3 * P1;
    for (int u = tid; u < SPAN; u += 256) {
        int p = p0 - S - 1 + u;
        union { unsigned short us[4]; uint2 u2; } o;
        o.u2 = (uint2){0u, 0u};
        if (p >= 0 && p < P) {
            o.us[0] = bf16bits(in[p]);
            o.us[1] = bf16bits(in[P1 + p]);
            o.us[2] = bf16bits(in[2 * P1 + p]);
        }
        *(uint2*)(ls4 + u * 4) = o.u2;
    }
    const short8* wb = (const short8*)wpk1;
    short8 b0[4], b1[4];
    #pragma unroll
    for (int nt = 0; nt < 4; ++nt) {
        b0[nt] = wb[(size_t)(nt * 64 + lane)];
        b1[nt] = wb[(size_t)((4 + nt) * 64 + lane)];
    }
    int t0 = 2 * quad, t1 = t0 + 1;
    int d0 = (t0 / 3 - 1) * S + (t0 % 3 - 1);
    int d1 = (t1 / 3 - 1) * S + (t1 % 3 - 1);
    const int d8 = S + 1;
    int tx0 = t0 % 3, tx1 = t1 % 3;
    __syncthreads();
    f32x4 acc[4][4];
    #pragma unroll
    for (int mt = 0; mt < 4; ++mt)
        #pragma unroll
        for (int nt = 0; nt < 4; ++nt) acc[mt][nt] = (f32x4){0.f, 0.f, 0.f, 0.f};
    #pragma unroll
    for (int mt = 0; mt < 4; ++mt) {
        int pl = wv * 64 + mt * 16 + col;
        int xm = (p0 + pl) % S;
        int base = pl + S + 1;
        uint2 h0 = *(const uint2*)(ls4 + (base + d0) * 4);
        uint2 h1 = *(const uint2*)(ls4 + (base + d1) * 4);
        uint2 h8 = *(const uint2*)(ls4 + (base + d8) * 4);
        bool ok0 = (tx0 == 0) ? (xm >= 1) : ((tx0 == 2) ? (xm <= S - 2) : true);
        bool ok1 = (tx1 == 0) ? (xm >= 1) : ((tx1 == 2) ? (xm <= S - 2) : true);
        bool ok8 = (quad == 0) && (xm <= S - 2);
        if (!ok0) h0 = (uint2){0u, 0u};
        if (!ok1) h1 = (uint2){0u, 0u};
        if (!ok8) h8 = (uint2){0u, 0u};
        union { uint4 u; short8 s; } ca, cb;
        ca.u = (uint4){h0.x, h0.y, h1.x, h1.y};
        cb.u = (uint4){h8.x, h8.y, 0u, 0u};
        #pragma unroll
        for (int nt = 0; nt < 4; ++nt) {
            acc[mt][nt] = __builtin_amdgcn_mfma_f32_16x16x32_bf16(ca.s, b0[nt], acc[mt][nt], 0, 0, 0);
            acc[mt][nt] = __builtin_amdgcn_mfma_f32_16x16x32_bf16(cb.s, b1[nt], acc[mt][nt], 0, 0, 0);
        }
    }
    float s[4] = {0.f, 0.f, 0.f, 0.f}, s2[4] = {0.f, 0.f, 0.f, 0.f};
    __hip_bfloat16* ob = xpool + (size_t)img * PX * 64;
    #pragma unroll
    for (int mt = 0; mt < 4; ++mt) {
        int tb = p0 + wv * 64 + mt * 16 + quad * 4;
        #pragma unroll
        for (int reg = 0; reg < 4; ++reg) {
            int pr = tb + reg;
            if (pr < P) {
                #pragma unroll
                for (int nt = 0; nt < 4; ++nt) {
                    float v = acc[mt][nt][reg];
                    s[nt] += v;
                    s2[nt] = fmaf(v, v, s2[nt]);
                }
            }
        }
        #pragma unroll
        for (int pr2 = 0; pr2 < 2; ++pr2) {
            int m0 = tb + pr2 * 2;
            if (m0 < P) {
                #pragma unroll
                for (int nt = 0; nt < 4; ++nt) {
                    float v = fmaxf(acc[mt][nt][pr2 * 2], acc[mt][nt][pr2 * 2 + 1]);
                    ob[(size_t)(m0 >> 1) * 64 + nt * 16 + col] = __float2bfloat16(v);
                }
            }
        }
    }
    #pragma unroll
    for (int d = 16; d < 64; d <<= 1)
        #pragma unroll
        for (int nt = 0; nt < 4; ++nt) {
            s[nt] += __shfl_xor(s[nt], d, 64);
            s2[nt] += __shfl_xor(s2[nt], d, 64);
        }
    if (quad == 0) {
        #pragma unroll
        for (int nt = 0; nt < 4; ++nt) {
            qs[wv][nt * 16 + col] = s[nt];
            qs2[wv][nt * 16 + col] = s2[nt];
        }
    }
    __syncthreads();
    if (wv == 0) {
        int g = (img < NQ) ? 0 : 1 + (img - NQ) / SHOT;
        int rep = blockIdx.x & (NREP - 1);
        float ts = qs[0][lane] + qs[1][lane] + qs[2][lane] + qs[3][lane];
        float ts2 = qs2[0][lane] + qs2[1][lane] + qs2[2][lane] + qs2[3][lane];
        float* base = sums + ((size_t)(g * 64 + lane) * 2) * NREP + rep;
        atomicAdd(base, ts);
        atomicAdd(base + NREP, ts2);
    }
}

// block-level BN finalize: reduce prev-stage sums (64ch x 2 x NREP) -> LDS (a,b) pairs.
template <int PREVP>
__device__ __forceinline__ void bn_fold(const float* __restrict__ sums_prev,
                                        const float* __restrict__ gamma,
                                        const float* __restrict__ beta,
                                        int g, int tid, float* msl)
{
    if (tid < 64) {
        const float* ps = sums_prev + (size_t)(g * 64 + tid) * 2 * NREP;
        float s = 0.f, s2 = 0.f;
        #pragma unroll
        for (int r = 0; r < NREP; ++r) { s += ps[r]; s2 += ps[NREP + r]; }
        float cnt = (float)((g == 0 ? NQ : SHOT) * PREVP);
        float mean = s / cnt;
        float var = s2 / cnt - mean * mean;
        float a = rsqrtf(var + EPSB) * gamma[tid];
        msl[tid * 2] = a;
        msl[tid * 2 + 1] = fmaf(-mean, a, beta[tid]);
    }
}

// ------- MFMA conv 64->64. Staging MODE: 1 = BN+LReLU on bf16 raw;
//         2 = y-pair max on x-pooled raw [2S x S] + BN + LReLU (fused bnpooly).
//         BN fold (prev-stage stats) computed per block in the prologue (no finalize kernel).
//         Output raw bf16; POOLX adds in-register x-pair max (out [P/2]).
//         MBLK halved vs earlier rounds (conv2: 256->128, conv3/4: 128->64) so the grids
//         fill the 256 CUs with >=1.5 blocks/CU for wave-level latency hiding.
template <int S, int MBLK, int MODE, bool POOLX, int PREVP>
__global__ __launch_bounds__(256) void conv64m_k(const unsigned short* __restrict__ inv,
                                                 const unsigned short* __restrict__ wpk,
                                                 __hip_bfloat16* __restrict__ out,
                                                 float* __restrict__ sums,
                                                 const float* __restrict__ sums_prev,
                                                 const float* __restrict__ gamma,
                                                 const float* __restrict__ beta)
{
    constexpr int P = S * S;
    constexpr int MT = MBLK / 64;
    constexpr int NB = (P + MBLK - 1) / MBLK;
    constexpr int SPAN = MBLK + 2 * S + 2;
    __shared__ __align__(16) unsigned short ls[SPAN * 72];
    __shared__ float qs[4][64], qs2[4][64];
    __shared__ float msl[128];
    int img = blockIdx.x / NB;
    int p0 = (blockIdx.x % NB) * MBLK;
    int tid = threadIdx.x;
    int lane = tid & 63, wv = tid >> 6;
    int col = lane & 15, quad = lane >> 4;
    int g = (img < NQ) ? 0 : 1 + (img - NQ) / SHOT;
    bn_fold<PREVP>(sums_prev, gamma, beta, g, tid, msl);
    __syncthreads();
    {
        int part = tid & 7;
        float ba[8], bb[8];
        #pragma unroll
        for (int j = 0; j < 8; ++j) {
            ba[j] = msl[(part * 8 + j) * 2];
            bb[j] = msl[(part * 8 + j) * 2 + 1];
        }
        if constexpr (MODE == 1) {
            const unsigned short* ib = inv + (size_t)img * P * 64;
            for (int u = tid; u < SPAN * 8; u += 256) {
                int pix = u >> 3;
                int p = p0 - S - 1 + pix;
                union { unsigned short us[8]; short8 s8; } o;
                #pragma unroll
                for (int j = 0; j < 8; ++j) o.us[j] = 0;
                if (p >= 0 && p < P) {
                    union { short8 s8; unsigned short us[8]; } x;
                    x.s8 = *(const short8*)(ib + (size_t)p * 64 + part * 8);
                    #pragma unroll
                    for (int j = 0; j < 8; ++j) {
                        float v = fmaf(bits2f(x.us[j]), ba[j], bb[j]);
                        v = fmaxf(v, SLOPE * v);
                        o.us[j] = bf16bits(v);
                    }
                }
                *(short8*)(ls + pix * 72 + part * 8) = o.s8;
            }
        } else {
            // MODE 2: input is x-pooled raw of previous conv: [2S rows][S wide], 64ch
            const unsigned short* ib2 = inv + (size_t)img * (2 * (size_t)P) * 64;
            for (int u = tid; u < SPAN * 8; u += 256) {
                int pix = u >> 3;
                int p = p0 - S - 1 + pix;
                union { unsigned short us[8]; short8 s8; } o;
                #pragma unroll
                for (int j = 0; j < 8; ++j) o.us[j] = 0;
                if (p >= 0 && p < P) {
                    int y = p / S, x = p - y * S;
                    const unsigned short* src = ib2 + ((size_t)(2 * y) * S + x) * 64 + part * 8;
                    union { short8 s8; unsigned short us[8]; } x0, x1;
                    x0.s8 = *(const short8*)src;
                    x1.s8 = *(const short8*)(src + (size_t)S * 64);
                    #pragma unroll
                    for (int j = 0; j < 8; ++j) {
                        float v = fmaxf(bits2f(x0.us[j]), bits2f(x1.us[j]));
                        v = fmaf(v, ba[j], bb[j]);
                        v = fmaxf(v, SLOPE * v);
                        o.us[j] = bf16bits(v);
                    }
                }
                *(short8*)(ls + pix * 72 + part * 8) = o.s8;
            }
        }
    }
    __syncthreads();
    f32x4 acc[MT][4];
    #pragma unroll
    for (int mt = 0; mt < MT; ++mt)
        #pragma unroll
        for (int nt = 0; nt < 4; ++nt) acc[mt][nt] = (f32x4){0.f, 0.f, 0.f, 0.f};
    bool mok0[MT], mok2[MT];
    #pragma unroll
    for (int mt = 0; mt < MT; ++mt) {
        int xm = (p0 + wv * (MT * 16) + mt * 16 + col) % S;
        mok0[mt] = xm >= 1;
        mok2[mt] = xm <= S - 2;
    }
    const short8* wb = (const short8*)wpk;
    #pragma unroll
    for (int ky = 0; ky < 3; ++ky) {
        #pragma unroll
        for (int kx = 0; kx < 3; ++kx) {
            int t = ky * 3 + kx;
            int d = (ky - 1) * S + (kx - 1);
            #pragma unroll
            for (int half = 0; half < 2; ++half) {
                short8 b[4];
                #pragma unroll
                for (int nt = 0; nt < 4; ++nt)
                    b[nt] = wb[((t * 2 + half) * 4 + nt) * 64 + lane];
                #pragma unroll
                for (int mt = 0; mt < MT; ++mt) {
                    int idx = wv * (MT * 16) + mt * 16 + col + S + 1 + d;
                    short8 a = *(const short8*)(ls + idx * 72 + half * 32 + quad * 8);
                    bool ok = (kx == 0) ? mok0[mt] : (kx == 2) ? mok2[mt] : true;
                    if (!ok) a = (short8){0, 0, 0, 0, 0, 0, 0, 0};
                    #pragma unroll
                    for (int nt = 0; nt < 4; ++nt)
                        acc[mt][nt] = __builtin_amdgcn_mfma_f32_16x16x32_bf16(a, b[nt], acc[mt][nt], 0, 0, 0);
                }
            }
        }
    }
    float s[4] = {0.f, 0.f, 0.f, 0.f}, s2[4] = {0.f, 0.f, 0.f, 0.f};
    __hip_bfloat16* ob = out + (size_t)img * (POOLX ? P / 2 : P) * 64;
    #pragma unroll
    for (int mt = 0; mt < MT; ++mt) {
        int tb = p0 + wv * (MT * 16) + mt * 16 + quad * 4;
        #pragma unroll
        for (int reg = 0; reg < 4; ++reg) {
            int pr = tb + reg;
            if (pr < P) {
                #pragma unroll
                for (int nt = 0; nt < 4; ++nt) {
                    float v = acc[mt][nt][reg];
                    s[nt] += v;
                    s2[nt] = fmaf(v, v, s2[nt]);
                }
            }
        }
        if constexpr (POOLX) {
            #pragma unroll
            for (int pr2 = 0; pr2 < 2; ++pr2) {
                int m0 = tb + pr2 * 2;
                if (m0 < P) {
                    #pragma unroll
                    for (int nt = 0; nt < 4; ++nt) {
                        float v = fmaxf(acc[mt][nt][pr2 * 2], acc[mt][nt][pr2 * 2 + 1]);
                        ob[(size_t)(m0 >> 1) * 64 + nt * 16 + col] = __float2bfloat16(v);
                    }
                }
            }
        } else {
            #pragma unroll
            for (int reg = 0; reg < 4; ++reg) {
                int pr = tb + reg;
                if (pr < P) {
                    #pragma unroll
                    for (int nt = 0; nt < 4; ++nt)
                        ob[(size_t)pr * 64 + nt * 16 + col] = __float2bfloat16(acc[mt][nt][reg]);
                }
            }
        }
    }
    #pragma unroll
    for (int d = 16; d < 64; d <<= 1)
        #pragma unroll
        for (int nt = 0; nt < 4; ++nt) {
            s[nt] += __shfl_xor(s[nt], d, 64);
            s2[nt] += __shfl_xor(s2[nt], d, 64);
        }
    if (quad == 0) {
        #pragma unroll
        for (int nt = 0; nt < 4; ++nt) {
            qs[wv][nt * 16 + col] = s[nt];
            qs2[wv][nt * 16 + col] = s2[nt];
        }
    }
    __syncthreads();
    if (wv == 0) {
        int rep = blockIdx.x & (NREP - 1);
        float ts = qs[0][lane] + qs[1][lane] + qs[2][lane] + qs[3][lane];
        float ts2 = qs2[0][lane] + qs2[1][lane] + qs2[2][lane] + qs2[3][lane];
        float* base = sums + ((size_t)(g * 64 + lane) * 2) * NREP + rep;
        atomicAdd(base, ts);
        atomicAdd(base + NREP, ts2);
    }
}

// ---- BN4 fold + BN + LeakyReLU + per-pixel L2-normalize, 32 pixels/block ----
__global__ __launch_bounds__(256) void bnnorm_k(const unsigned short* __restrict__ x,
                                                const float* __restrict__ sums_prev,
                                                const float* __restrict__ g4,
                                                const float* __restrict__ b4,
                                                __hip_bfloat16* __restrict__ out)
{
    __shared__ float msl[2][128];          // group-specific fold: both groups computed
    int tid = threadIdx.x;
    int pix0 = blockIdx.x * BNPIX;
    int imgA = pix0 / P3;
    int plast = pix0 + BNPIX - 1; if (plast >= NIMG * P3) plast = NIMG * P3 - 1;
    int imgB = plast / P3;
    int ga = (imgA < NQ) ? 0 : 1 + (imgA - NQ) / SHOT;
    int gb = (imgB < NQ) ? 0 : 1 + (imgB - NQ) / SHOT;
    bn_fold<P3>(sums_prev, g4, b4, ga, tid, msl[0]);
    if (gb != ga) bn_fold<P3>(sums_prev, g4, b4, gb, tid, msl[1]);
    __syncthreads();
    int lane = tid & 63, wvr = tid >> 6;
    int pbase = pix0 + wvr * 8;            // 8 pixels per wave
    float v[8];
    #pragma unroll
    for (int i = 0; i < 8; ++i) {          // independent loads first (MLP)
        int pix = pbase + i;
        v[i] = (pix < NIMG * P3) ? bits2f(x[(size_t)pix * 64 + lane]) : 0.f;
    }
    #pragma unroll
    for (int i = 0; i < 8; ++i) {
        int pix = pbase + i;
        if (pix >= NIMG * P3) break;       // wave-uniform
        int img = pix / P3;
        int g = (img < NQ) ? 0 : 1 + (img - NQ) / SHOT;
        const float* ms = msl[(g == ga) ? 0 : 1];
        float w = fmaf(v[i], ms[lane * 2], ms[lane * 2 + 1]);
        w = w >= 0.f ? w : SLOPE * w;
        float ss = w * w;
        #pragma unroll
        for (int d = 32; d > 0; d >>= 1) ss += __shfl_xor(ss, d, 64);
        out[(size_t)pix * 64 + lane] = __float2bfloat16(w * rsqrtf(ss));
    }
}

// ---------------- similarity: m-split blocks, dbuf LDS chunks, partial top-3 + merge -------
// (proven 49.8us shape: dbuf, one barrier/chunk, QG=2, no gate)
__device__ __forceinline__ void ins3(float v, float& t0, float& t1, float& t2)
{
    t2 = __builtin_amdgcn_fmed3f(v, t1, t2);
    t1 = __builtin_amdgcn_fmed3f(v, t0, t1);
    t0 = fmaxf(t0, v);
}

// merge lane^xor partner's sorted top-3 via ds_swizzle (BitMode: (xor<<10)|0x1F)
template <int PAT>
__device__ __forceinline__ void swzmerge(float& t0, float& t1, float& t2)
{
    float u0 = __int_as_float(__builtin_amdgcn_ds_swizzle(__float_as_int(t0), PAT));
    float u1 = __int_as_float(__builtin_amdgcn_ds_swizzle(__float_as_int(t1), PAT));
    float u2 = __int_as_float(__builtin_amdgcn_ds_swizzle(__float_as_int(t2), PAT));
    ins3(u0, t0, t1, t2);
    ins3(u1, t0, t1, t2);
    ins3(u2, t0, t1, t2);
}

// grid: bq(32) x n(5) x qb(4) x mr(2) = 1280 blocks.
__global__ __launch_bounds__(256) void sim_part_k(const __hip_bfloat16* __restrict__ fhat,
                                                  float* __restrict__ part)
{
    __shared__ __align__(16) unsigned short sl[2][64 * SLS];
    int t = blockIdx.x;
    int mr = t & 1;
    int qb = (t >> 1) & 3;
    int n = (t >> 3) % NCLS;
    int bq = t / (8 * NCLS);
    int tid = threadIdx.x, lane = tid & 63, wv = tid >> 6;
    int col = lane & 15, quad = lane >> 4;
    short8 a0[QG], a1[QG];
    #pragma unroll
    for (int g = 0; g < QG; ++g) {
        int q = qb * QBLK + wv * (QG * 16) + g * 16 + col;
        int qc = q < P3 ? q : P3 - 1;
        const unsigned short* qp = (const unsigned short*)fhat + ((size_t)bq * P3 + qc) * 64;
        a0[g] = *(const short8*)(qp + quad * 8);
        a1[g] = *(const short8*)(qp + 32 + quad * 8);
    }
    const unsigned short* sp = (const unsigned short*)fhat + (size_t)(NQ + n * SHOT) * P3 * 64;
    int m_lo = mr * MSPAN;
    int m_cnt = MM - m_lo; if (m_cnt > MSPAN) m_cnt = MSPAN;
    int nfull = m_cnt >> 6;                // 18, 16
    int rem = m_cnt & 63;                  // 0, 29   (rem < 32 always)
    float t0[QG][4], t1[QG][4], t2[QG][4];
    #pragma unroll
    for (int g = 0; g < QG; ++g)
        #pragma unroll
        for (int r = 0; r < 4; ++r) { t0[g][r] = NEGINF; t1[g][r] = NEGINF; t2[g][r] = NEGINF; }
    int srow = tid >> 3, scc = (tid & 7) * 8;
    const unsigned short* gp = sp + (size_t)(m_lo + srow) * 64 + scc;
    unsigned short* ld0 = &sl[0][srow * SLS + scc];
    unsigned short* ld1 = &sl[1][srow * SLS + scc];
    const short8 z8 = {0, 0, 0, 0, 0, 0, 0, 0};
    // prologue: chunk 0 is always full
    short8 v0 = *(const short8*)gp;
    short8 v1 = *(const short8*)(gp + 32 * 64);
    *(short8*)ld0 = v0;
    *(short8*)(ld0 + 32 * SLS) = v1;
    __syncthreads();
    int cur = 0;
    for (int c = 0; c < nfull; ++c) {
        bool nf = (c + 1 < nfull);
        bool np = (c + 1 == nfull) && (rem != 0);
        if (nf) {                          // issue next full chunk's loads early
            gp += 64 * 64;
            v0 = *(const short8*)gp;
            v1 = *(const short8*)(gp + 32 * 64);
        } else if (np) {                   // partial chunk's loads (rem<32: v1 all zero)
            gp += 64 * 64;
            v0 = (srow < rem) ? *(const short8*)gp : z8;
            v1 = z8;
        }
        const unsigned short* sr = &sl[cur][col * SLS + quad * 8];
        #pragma unroll
        for (int mt = 0; mt < 4; ++mt) {   // branch-free: full chunk, all tiles valid
            short8 b0 = *(const short8*)(sr + mt * (16 * SLS));
            short8 b1 = *(const short8*)(sr + mt * (16 * SLS) + 32);
            #pragma unroll
            for (int g = 0; g < QG; ++g) {
                f32x4 acc = {0.f, 0.f, 0.f, 0.f};
                acc = __builtin_amdgcn_mfma_f32_16x16x32_bf16(a0[g], b0, acc, 0, 0, 0);
                acc = __builtin_amdgcn_mfma_f32_16x16x32_bf16(a1[g], b1, acc, 0, 0, 0);
                #pragma unroll
                for (int r = 0; r < 4; ++r) ins3(acc[r], t0[g][r], t1[g][r], t2[g][r]);
            }
        }
        if (nf | np) {                     // write next chunk into the other buffer
            unsigned short* ld = (cur == 0) ? ld1 : ld0;
            *(short8*)ld = v0;
            *(short8*)(ld + 32 * SLS) = v1;
        }
        __syncthreads();
        cur ^= 1;
    }
    if (rem) {                             // peeled partial chunk (mr=1 only): mask fake rows
        const unsigned short* sr = &sl[cur][col * SLS + quad * 8];
        int ptiles = (rem + 15) >> 4;      // 2
        for (int mt = 0; mt < ptiles; ++mt) {
            short8 b0 = *(const short8*)(sr + mt * (16 * SLS));
            short8 b1 = *(const short8*)(sr + mt * (16 * SLS) + 32);
            bool valid = (mt * 16 + col) < rem;
            #pragma unroll
            for (int g = 0; g < QG; ++g) {
                f32x4 acc = {0.f, 0.f, 0.f, 0.f};
                acc = __builtin_amdgcn_mfma_f32_16x16x32_bf16(a0[g], b0, acc, 0, 0, 0);
                acc = __builtin_amdgcn_mfma_f32_16x16x32_bf16(a1[g], b1, acc, 0, 0, 0);
                #pragma unroll
                for (int r = 0; r < 4; ++r)
                    ins3(valid ? acc[r] : NEGINF, t0[g][r], t1[g][r], t2[g][r]);
            }
        }
    }
    // butterfly merge across the 16 cols (m residues) via ds_swizzle
    #pragma unroll
    for (int g = 0; g < QG; ++g)
        #pragma unroll
        for (int r = 0; r < 4; ++r) {
            swzmerge<0x041F>(t0[g][r], t1[g][r], t2[g][r]);
            swzmerge<0x081F>(t0[g][r], t1[g][r], t2[g][r]);
            swzmerge<0x101F>(t0[g][r], t1[g][r], t2[g][r]);
            swzmerge<0x201F>(t0[g][r], t1[g][r], t2[g][r]);
        }
    if (col == 0) {
        #pragma unroll
        for (int g = 0; g < QG; ++g)
            #pragma unroll
            for (int r = 0; r < 4; ++r) {
                int ql = wv * (QG * 16) + g * 16 + quad * 4 + r;
                float* pp = part + ((((size_t)(bq * NCLS + n) * NQB + qb) * MRNG + mr) * QBLK + ql) * 3;
                pp[0] = t0[g][r];
                pp[1] = t1[g][r];
                pp[2] = t2[g][r];
            }
    }
}

// one block per (bq, n): merge 2 m-range partials per q, sum top-3, write out directly
__global__ __launch_bounds__(256) void sim_merge_k(const float* __restrict__ part,
                                                   float* __restrict__ out)
{
    __shared__ float red[4];
    int b = blockIdx.x;                    // bq*NCLS + n
    int tid = threadIdx.x, lane = tid & 63, wv = tid >> 6;
    float s = 0.f;
    for (int q = tid; q < P3; q += 256) {
        int qb = q >> 7, ql = q & 127;
        const float* pp = part + (((size_t)b * NQB + qb) * MRNG * QBLK + ql) * 3;
        float v0 = pp[0], v1 = pp[1], v2 = pp[2];
        #pragma unroll
        for (int mr = 1; mr < MRNG; ++mr) {
            const float* pm = pp + (size_t)mr * (QBLK * 3);
            ins3(pm[0], v0, v1, v2);
            ins3(pm[1], v0, v1, v2);
            ins3(pm[2], v0, v1, v2);
        }
        s += v0 + v1 + v2;
    }
    #pragma unroll
    for (int d = 32; d > 0; d >>= 1) s += __shfl_xor(s, d, 64);
    if (lane == 0) red[wv] = s;
    __syncthreads();
    if (tid == 0) out[b] = red[0] + red[1] + red[2] + red[3];
}

extern "C" void kernel_launch(void* const* d_in, const int* in_sizes, int n_in,
                              void* d_out, int out_size, void* d_ws, size_t ws_size,
                              hipStream_t stream)
{
    const float* input1 = (const float*)d_in[0];
    const float* input2 = (const float*)d_in[1];
    const float* w1 = (const float*)d_in[2];
    const float* g1 = (const float*)d_in[3];
    const float* b1 = (const float*)d_in[4];
    const float* w2 = (const float*)d_in[5];
    const float* g2 = (const float*)d_in[6];
    const float* b2 = (const float*)d_in[7];
    const float* w3 = (const float*)d_in[8];
    const float* g3 = (const float*)d_in[9];
    const float* b3 = (const float*)d_in[10];
    const float* w4 = (const float*)d_in[11];
    const float* g4 = (const float*)d_in[12];
    const float* b4 = (const float*)d_in[13];
    float* out = (float*)d_out;

    char* w8 = (char*)d_ws;
    const size_t oB = 51480576;
    const size_t oT = oB + 12870144;
    const size_t STG = 6 * 64 * 2 * NREP * sizeof(float);   // 98304 B per stage
    __hip_bfloat16* xpool1 = (__hip_bfloat16*)(w8 + 0);     // [57][3528][64] bf16 25.7MB
    __hip_bfloat16* conv3raw = (__hip_bfloat16*)(w8 + 0);   // reuse A: [57][441][64] bf16 3.2MB
    __hip_bfloat16* conv4raw = (__hip_bfloat16*)(w8 + 9652608);  // 3.2MB bf16
    __hip_bfloat16* fhat = (__hip_bfloat16*)(w8 + 16087680);
    __hip_bfloat16* xpool2 = (__hip_bfloat16*)(w8 + oB);    // [57][882][64] bf16 6.44MB
    float* sums = (float*)(w8 + oT);                        // 4 stages x 98304 B
    unsigned short* wpk2 = (unsigned short*)(w8 + oT + 4 * STG + 12288);
    unsigned short* wpk3 = (unsigned short*)(w8 + oT + 4 * STG + 12288 + 73728);
    unsigned short* wpk4 = (unsigned short*)(w8 + oT + 4 * STG + 12288 + 147456);
    unsigned short* wpk1 = (unsigned short*)(w8 + oT + 4 * STG + 12288 + 221184);
    const size_t oP = oT + 4 * STG + 12288 + 221184 + 8192;
    float* part = (float*)(w8 + oP);                        // 32*5*4*2*128*3 f32 = 1.97MB
    if (ws_size < oP + (size_t)NQ * NCLS * NQB * MRNG * QBLK * 3 * sizeof(float)) return;
    float* sums1 = sums;
    float* sums2 = sums + 6 * 64 * 2 * NREP;
    float* sums3 = sums2 + 6 * 64 * 2 * NREP;
    float* sums4 = sums3 + 6 * 64 * 2 * NREP;

    // pack weights + zero stats (no memsets needed; sim_merge overwrites all of d_out)
    pack_all_k<<<448, 256, 0, stream>>>(w1, w2, w3, w4, wpk1, wpk2, wpk3, wpk4, sums);

    // stage 1: conv1 MFMA + in-register x-pool (+stats)
    conv1m_k<<<NIMG * 28, 256, 0, stream>>>(input1, input2, wpk1, xpool1, sums1);
    // stage 2: conv2, BN1 folded per block, y-pool+BN+LReLU staging, x-pool out
    // MBLK=128 (proven MT=2 path): 798 blocks = 3.1/CU for latency hiding
    conv64m_k<42, 128, 2, true, P1><<<NIMG * 14, 256, 0, stream>>>(
        (const unsigned short*)xpool1, wpk2, xpool2, sums2, sums1, g1, b1);
    // stage 3: conv3, BN2 folded; MBLK=64 (MT=1): 399 blocks = 1.6/CU
    conv64m_k<21, 64, 2, false, P2><<<NIMG * 7, 256, 0, stream>>>(
        (const unsigned short*)xpool2, wpk3, conv3raw, sums3, sums2, g2, b2);
    // stage 4: conv4, BN3 folded; MBLK=64 (MT=1): 399 blocks
    conv64m_k<21, 64, 1, false, P3><<<NIMG * 7, 256, 0, stream>>>(
        (const unsigned short*)conv3raw, wpk4, conv4raw, sums4, sums3, g3, b3);
    // BN4 fold + BN + LReLU + L2-normalize (32 pixels/block)
    bnnorm_k<<<(NIMG * P3 + BNPIX - 1) / BNPIX, 256, 0, stream>>>(
        (const unsigned short*)conv4raw, sums4, g4, b4, fhat);
    // similarity: partial top-3 over m-ranges, then merge (writes d_out directly)
    sim_part_k<<<NQ * NCLS * NQB * MRNG, 256, 0, stream>>>(fhat, part);
    sim_merge_k<<<NQ * NCLS, 256, 0, stream>>>(part, out);
}